// Round 1
// baseline (56.658 us; speedup 1.0000x reference)
//
#include <hip/hip_runtime.h>

// DLGN_VT: out[b] = sum_{ijk} g1[b,i] g2[b,j] g3[b,k] V[i,j,k]
// g_m = sigmoid(30 * x @ Wm^T),  B=4096, D=128, N=32.
//
// Kernel 1: gates -> G[b][96] f32 in d_ws (features 0..31=g1, 32..63=g2, 64..95=g3)
// Kernel 2: per-lane (b), per-wave (i) factored contraction, atomicAdd into out.

#define BETA 30.0f

__device__ __forceinline__ float f4c(const float4 v, int c) {
    // compile-time c after full unroll -> folds to a register pick
    return c == 0 ? v.x : (c == 1 ? v.y : (c == 2 ? v.z : v.w));
}

__global__ __launch_bounds__(256) void gates_kernel(
    const float* __restrict__ x,
    const float* __restrict__ W1,
    const float* __restrict__ W2,
    const float* __restrict__ W3,
    float* __restrict__ G)
{
    const int t = blockIdx.x * 256 + threadIdx.x;   // [0, 4096*96)
    const int b = t / 96;
    const int f = t - b * 96;

    const float* W = (f < 32) ? (W1 + f * 128)
                   : (f < 64) ? (W2 + (f - 32) * 128)
                              : (W3 + (f - 64) * 128);
    const float4* x4 = (const float4*)(x + b * 128);
    const float4* w4 = (const float4*)W;

    float acc = 0.f;
#pragma unroll
    for (int c = 0; c < 32; ++c) {
        const float4 xv = x4[c];
        const float4 wv = w4[c];
        acc = fmaf(xv.x, wv.x, acc);
        acc = fmaf(xv.y, wv.y, acc);
        acc = fmaf(xv.z, wv.z, acc);
        acc = fmaf(xv.w, wv.w, acc);
    }
    // sigmoid(BETA*acc); saturates correctly at +-inf
    const float g = 1.0f / (1.0f + __expf(-BETA * acc));
    G[t] = g;   // G[b*96 + f], coalesced since t is the flat index
}

__global__ __launch_bounds__(256) void contract_kernel(
    const float* __restrict__ G,
    const float* __restrict__ V,
    float* __restrict__ out)
{
    const int l = threadIdx.x & 63;    // lane -> b
    const int w = threadIdx.x >> 6;    // wave -> i within chunk
    const int b = blockIdx.x * 64 + l;
    const int i = blockIdx.y * 4 + w;  // [0,32)

    // load g2[32], g3[32] into registers (all indices compile-time)
    const float4* Gr = (const float4*)(G + b * 96);
    float4 a2[8], a3[8];
#pragma unroll
    for (int c = 0; c < 8; ++c) {
        a2[c] = Gr[8 + c];    // g2: floats 32..63
        a3[c] = Gr[16 + c];   // g3: floats 64..95
    }
    const float g1 = G[b * 96 + i];

    const float4* V4 = (const float4*)(V + i * 1024);  // V[i][j][k], wave-uniform addr
    float si = 0.f;
#pragma unroll
    for (int j = 0; j < 32; ++j) {
        float tj = 0.f;
#pragma unroll
        for (int c = 0; c < 8; ++c) {
            const float4 v = V4[j * 8 + c];
            const float4 g3v = a3[c];
            tj = fmaf(v.x, g3v.x, tj);
            tj = fmaf(v.y, g3v.y, tj);
            tj = fmaf(v.z, g3v.z, tj);
            tj = fmaf(v.w, g3v.w, tj);
        }
        const float g2j = f4c(a2[j >> 2], j & 3);
        si = fmaf(g2j, tj, si);
    }
    atomicAdd(&out[b], g1 * si);
}

extern "C" void kernel_launch(void* const* d_in, const int* in_sizes, int n_in,
                              void* d_out, int out_size, void* d_ws, size_t ws_size,
                              hipStream_t stream) {
    const float* x  = (const float*)d_in[0];
    const float* W1 = (const float*)d_in[1];
    const float* W2 = (const float*)d_in[2];
    const float* W3 = (const float*)d_in[3];
    const float* V  = (const float*)d_in[4];
    float* out = (float*)d_out;
    float* G   = (float*)d_ws;   // 4096*96*4 = 1.5 MB

    hipMemsetAsync(d_out, 0, (size_t)out_size * sizeof(float), stream);
    // gates: 4096 b * 96 features, one thread each
    gates_kernel<<<dim3(1536), dim3(256), 0, stream>>>(x, W1, W2, W3, G);
    // contraction: 64 b-chunks x 8 i-chunks, 256 threads (4 waves, wave->i)
    contract_kernel<<<dim3(64, 8), dim3(256), 0, stream>>>(G, V, out);
}

// Round 2
// 52.117 us; speedup vs baseline: 1.0871x; 1.0871x over previous
//
#include <hip/hip_runtime.h>

// DLGN_VT: out[b] = sum_{ijk} g1[b,i] g2[b,j] g3[b,k] V[i,j,k]
// g_m = sigmoid(30 * x @ Wm^T),  B=4096, D=128, N=32.
//
// Kernel 1: gates -> G[b][96] f32 in d_ws (features 0..31=g1, 32..63=g2, 64..95=g3)
//           ALSO zeroes out[] (replaces the pathological 39us fillBuffer dispatch).
// Kernel 2: per-lane (b), per-wave (i) factored contraction, atomicAdd into out.

#define BETA 30.0f

__device__ __forceinline__ float f4c(const float4 v, int c) {
    // compile-time c after full unroll -> folds to a register pick
    return c == 0 ? v.x : (c == 1 ? v.y : (c == 2 ? v.z : v.w));
}

__global__ __launch_bounds__(256) void gates_kernel(
    const float* __restrict__ x,
    const float* __restrict__ W1,
    const float* __restrict__ W2,
    const float* __restrict__ W3,
    float* __restrict__ G,
    float* __restrict__ out)
{
    const int t = blockIdx.x * 256 + threadIdx.x;   // [0, 4096*96)

    // zero the output accumulator (first 4096 threads); runs before
    // contract_kernel by stream ordering -> no separate memset dispatch
    if (t < 4096) out[t] = 0.f;

    const int b = t / 96;
    const int f = t - b * 96;

    const float* W = (f < 32) ? (W1 + f * 128)
                   : (f < 64) ? (W2 + (f - 32) * 128)
                              : (W3 + (f - 64) * 128);
    const float4* x4 = (const float4*)(x + b * 128);
    const float4* w4 = (const float4*)W;

    float acc = 0.f;
#pragma unroll
    for (int c = 0; c < 32; ++c) {
        const float4 xv = x4[c];
        const float4 wv = w4[c];
        acc = fmaf(xv.x, wv.x, acc);
        acc = fmaf(xv.y, wv.y, acc);
        acc = fmaf(xv.z, wv.z, acc);
        acc = fmaf(xv.w, wv.w, acc);
    }
    // sigmoid(BETA*acc); saturates correctly at +-inf
    const float g = 1.0f / (1.0f + __expf(-BETA * acc));
    G[t] = g;   // G[b*96 + f], coalesced since t is the flat index
}

__global__ __launch_bounds__(256) void contract_kernel(
    const float* __restrict__ G,
    const float* __restrict__ V,
    float* __restrict__ out)
{
    const int l = threadIdx.x & 63;    // lane -> b
    const int w = threadIdx.x >> 6;    // wave -> i within chunk
    const int b = blockIdx.x * 64 + l;
    const int i = blockIdx.y * 4 + w;  // [0,32)

    // load g2[32], g3[32] into registers (all indices compile-time)
    const float4* Gr = (const float4*)(G + b * 96);
    float4 a2[8], a3[8];
#pragma unroll
    for (int c = 0; c < 8; ++c) {
        a2[c] = Gr[8 + c];    // g2: floats 32..63
        a3[c] = Gr[16 + c];   // g3: floats 64..95
    }
    const float g1 = G[b * 96 + i];

    const float4* V4 = (const float4*)(V + i * 1024);  // V[i][j][k], wave-uniform addr
    float si = 0.f;
#pragma unroll
    for (int j = 0; j < 32; ++j) {
        float tj = 0.f;
#pragma unroll
        for (int c = 0; c < 8; ++c) {
            const float4 v = V4[j * 8 + c];
            const float4 g3v = a3[c];
            tj = fmaf(v.x, g3v.x, tj);
            tj = fmaf(v.y, g3v.y, tj);
            tj = fmaf(v.z, g3v.z, tj);
            tj = fmaf(v.w, g3v.w, tj);
        }
        const float g2j = f4c(a2[j >> 2], j & 3);
        si = fmaf(g2j, tj, si);
    }
    atomicAdd(&out[b], g1 * si);
}

extern "C" void kernel_launch(void* const* d_in, const int* in_sizes, int n_in,
                              void* d_out, int out_size, void* d_ws, size_t ws_size,
                              hipStream_t stream) {
    const float* x  = (const float*)d_in[0];
    const float* W1 = (const float*)d_in[1];
    const float* W2 = (const float*)d_in[2];
    const float* W3 = (const float*)d_in[3];
    const float* V  = (const float*)d_in[4];
    float* out = (float*)d_out;
    float* G   = (float*)d_ws;   // 4096*96*4 = 1.5 MB

    // gates (+ out zeroing): 4096 b * 96 features, one thread each
    gates_kernel<<<dim3(1536), dim3(256), 0, stream>>>(x, W1, W2, W3, G, out);
    // contraction: 64 b-chunks x 8 i-chunks, 256 threads (4 waves, wave->i)
    contract_kernel<<<dim3(64, 8), dim3(256), 0, stream>>>(G, V, out);
}

// Round 3
// 48.356 us; speedup vs baseline: 1.1717x; 1.0778x over previous
//
#include <hip/hip_runtime.h>

// DLGN_VT fused single-dispatch:
//   out[b] = sum_{ijk} g1[b,i] g2[b,j] g3[b,k] V[i,j,k],  g_m = sigmoid(30 * x @ Wm^T)
//   B=4096, D=128, N=32.
//
// 512 blocks x 256 threads; block owns 8 batch rows.
// Phase 1: 8b x 96f = 768 gate dot-products (3/thread) -> LDS Gs[8][100] (padded).
// Phase 2: thread (b_loc=t&7, i=t>>3) computes g1[i] * sum_j g2[j] * (sum_k V[i,j,k] g3[k])
//          with g2/g3 held in 64 registers; reduce over i via shfl_xor + small LDS patch.
// No atomics, no global scratch, no memset, one dispatch.

#define BETA 30.0f

__device__ __forceinline__ float f4c(const float4 v, int c) {
    // compile-time c after full unroll -> folds to a register pick
    return c == 0 ? v.x : (c == 1 ? v.y : (c == 2 ? v.z : v.w));
}

__global__ __launch_bounds__(256) void dlgn_fused_kernel(
    const float* __restrict__ x,
    const float* __restrict__ W1,
    const float* __restrict__ W2,
    const float* __restrict__ W3,
    const float* __restrict__ V,
    float* __restrict__ out)
{
    __shared__ float Gs[8][100];   // padded: stride 100 (100%32=4) -> conflict-free phase-2 reads
    __shared__ float part[4][8];   // per-wave partial sums per b_loc

    const int t  = threadIdx.x;
    const int b0 = blockIdx.x * 8;

    // ---- Phase 1: gates. 768 dots = 8 b_loc x 96 features, 3 per thread ----
#pragma unroll
    for (int k = 0; k < 3; ++k) {
        const int d  = k * 256 + t;        // [0,768)
        const int bl = d / 96;             // compile-magic div
        const int f  = d - bl * 96;

        const float* W = (f < 32) ? (W1 + f * 128)
                       : (f < 64) ? (W2 + (f - 32) * 128)
                                  : (W3 + (f - 64) * 128);
        const float4* x4 = (const float4*)(x + (b0 + bl) * 128);
        const float4* w4 = (const float4*)W;

        float acc = 0.f;
#pragma unroll
        for (int c = 0; c < 32; ++c) {
            const float4 xv = x4[c];
            const float4 wv = w4[c];
            acc = fmaf(xv.x, wv.x, acc);
            acc = fmaf(xv.y, wv.y, acc);
            acc = fmaf(xv.z, wv.z, acc);
            acc = fmaf(xv.w, wv.w, acc);
        }
        Gs[bl][f] = 1.0f / (1.0f + __expf(-BETA * acc));
    }
    __syncthreads();

    // ---- Phase 2: contraction. thread -> (b_loc, i) ----
    const int bl = t & 7;
    const int i  = t >> 3;                 // [0,32)

    // preload g2[32], g3[32] into registers (compile-time indices only)
    const float4* Gr = (const float4*)&Gs[bl][0];   // row = 25 float4 (400 B, 16B-aligned)
    float4 a2[8], a3[8];
#pragma unroll
    for (int c = 0; c < 8; ++c) {
        a2[c] = Gr[8 + c];     // g2: floats 32..63
        a3[c] = Gr[16 + c];    // g3: floats 64..95
    }
    const float g1 = Gs[bl][i];

    const float4* V4 = (const float4*)(V + i * 1024);   // V[i][j][k]
    float si = 0.f;
#pragma unroll
    for (int j = 0; j < 32; ++j) {
        float tj = 0.f;
#pragma unroll
        for (int c = 0; c < 8; ++c) {
            const float4 v   = V4[j * 8 + c];
            const float4 g3v = a3[c];
            tj = fmaf(v.x, g3v.x, tj);
            tj = fmaf(v.y, g3v.y, tj);
            tj = fmaf(v.z, g3v.z, tj);
            tj = fmaf(v.w, g3v.w, tj);
        }
        const float g2j = f4c(a2[j >> 2], j & 3);
        si = fmaf(g2j, tj, si);
    }

    // ---- Reduce over i (bits 3..5 of lane) within wave, then across waves ----
    float v = g1 * si;
    v += __shfl_xor(v, 8);
    v += __shfl_xor(v, 16);
    v += __shfl_xor(v, 32);

    const int w = t >> 6;
    const int l = t & 63;
    if (l < 8) part[w][l] = v;
    __syncthreads();

    if (t < 8) out[b0 + t] = part[0][t] + part[1][t] + part[2][t] + part[3][t];
}

extern "C" void kernel_launch(void* const* d_in, const int* in_sizes, int n_in,
                              void* d_out, int out_size, void* d_ws, size_t ws_size,
                              hipStream_t stream) {
    const float* x  = (const float*)d_in[0];
    const float* W1 = (const float*)d_in[1];
    const float* W2 = (const float*)d_in[2];
    const float* W3 = (const float*)d_in[3];
    const float* V  = (const float*)d_in[4];
    float* out = (float*)d_out;

    dlgn_fused_kernel<<<dim3(512), dim3(256), 0, stream>>>(x, W1, W2, W3, V, out);
}

// Round 4
// 47.653 us; speedup vs baseline: 1.1890x; 1.0148x over previous
//
#include <hip/hip_runtime.h>

// DLGN_VT fused single-dispatch, v2 (latency-oriented rework):
//   out[b] = sum_{ijk} g1[b,i] g2[b,j] g3[b,k] V[i,j,k],  g_m = sigmoid(30 * x @ Wm^T)
//   B=4096, D=128, N=32.
//
// 1024 blocks x 256 threads; block owns 4 batch rows (b0..b0+3).
// Phase 1: 4 x 96 = 384 gate dots -> LDS Gs[4][100].
// Phase 2: thread t owns the disjoint V-subset {all i} x {j=t>>3} x {k-chunk c=t&7}:
//          per i ONE coalesced float4 load V4[i*256+t], reused across the 4 batch rows
//          (g3 chunks held in 16 registers). partial[b] = g2[b][j] * sum_i g1[b,i]*dot4(...).
//          Reduce partial over all 256 threads: 6x shfl_xor + 4x4 LDS patch.
// One dispatch, no atomics, no global scratch.

#define BETA 30.0f

__global__ __launch_bounds__(256, 4) void dlgn_fused2_kernel(
    const float* __restrict__ x,
    const float* __restrict__ W1,
    const float* __restrict__ W2,
    const float* __restrict__ W3,
    const float* __restrict__ V,
    float* __restrict__ out)
{
    __shared__ float Gs[4][100];   // padded row stride (100 % 32 == 4)
    __shared__ float part[4][4];   // [wave][b]

    const int t  = threadIdx.x;
    const int b0 = blockIdx.x * 4;

    // ---- Phase 1: gates. 384 dots = 4 b x 96 f; threads 0..255 then 0..127 ----
#pragma unroll
    for (int k = 0; k < 2; ++k) {
        const int d = k * 256 + t;
        if (d < 384) {
            const int bl = d / 96;
            const int f  = d - bl * 96;
            const float* W = (f < 32) ? (W1 + f * 128)
                           : (f < 64) ? (W2 + (f - 32) * 128)
                                      : (W3 + (f - 64) * 128);
            const float4* x4 = (const float4*)(x + (b0 + bl) * 128);
            const float4* w4 = (const float4*)W;
            float acc = 0.f;
#pragma unroll
            for (int c = 0; c < 32; ++c) {
                const float4 xv = x4[c];
                const float4 wv = w4[c];
                acc = fmaf(xv.x, wv.x, acc);
                acc = fmaf(xv.y, wv.y, acc);
                acc = fmaf(xv.z, wv.z, acc);
                acc = fmaf(xv.w, wv.w, acc);
            }
            Gs[bl][f] = 1.0f / (1.0f + __expf(-BETA * acc));
        }
    }
    __syncthreads();

    // ---- Phase 2: thread owns (j = t>>3, k-chunk c = t&7), all i, all 4 b ----
    const int j = t >> 3;   // [0,32)
    const int c = t & 7;    // [0,8) -> k chunk of 4

    // g3 chunk per batch row, held in registers
    float4 g3r[4];
#pragma unroll
    for (int b = 0; b < 4; ++b)
        g3r[b] = *(const float4*)&Gs[b][64 + c * 4];

    float s[4] = {0.f, 0.f, 0.f, 0.f};
    const float4* V4 = (const float4*)V;   // V[i][j][k] -> float4 idx i*256 + j*8 + c = i*256 + t

#pragma unroll
    for (int i = 0; i < 32; ++i) {
        const float4 v = V4[i * 256 + t];          // fully coalesced, disjoint per thread
#pragma unroll
        for (int b = 0; b < 4; ++b) {
            float d4 = v.x * g3r[b].x;
            d4 = fmaf(v.y, g3r[b].y, d4);
            d4 = fmaf(v.z, g3r[b].z, d4);
            d4 = fmaf(v.w, g3r[b].w, d4);
            s[b] = fmaf(Gs[b][i], d4, s[b]);       // * g1[b,i], uniform LDS broadcast
        }
    }

    // scale by g2[b][j]
    float p[4];
#pragma unroll
    for (int b = 0; b < 4; ++b)
        p[b] = s[b] * Gs[b][32 + j];

    // ---- Reduce over all 256 threads ----
#pragma unroll
    for (int off = 1; off < 64; off <<= 1) {
#pragma unroll
        for (int b = 0; b < 4; ++b)
            p[b] += __shfl_xor(p[b], off);
    }
    const int w = t >> 6;
    if ((t & 63) == 0) {
#pragma unroll
        for (int b = 0; b < 4; ++b)
            part[w][b] = p[b];
    }
    __syncthreads();

    if (t < 4)
        out[b0 + t] = part[0][t] + part[1][t] + part[2][t] + part[3][t];
}

extern "C" void kernel_launch(void* const* d_in, const int* in_sizes, int n_in,
                              void* d_out, int out_size, void* d_ws, size_t ws_size,
                              hipStream_t stream) {
    const float* x  = (const float*)d_in[0];
    const float* W1 = (const float*)d_in[1];
    const float* W2 = (const float*)d_in[2];
    const float* W3 = (const float*)d_in[3];
    const float* V  = (const float*)d_in[4];
    float* out = (float*)d_out;

    dlgn_fused2_kernel<<<dim3(1024), dim3(256), 0, stream>>>(x, W1, W2, W3, V, out);
}

// Round 5
// 20.740 us; speedup vs baseline: 2.7318x; 2.2976x over previous
//
#include <hip/hip_runtime.h>

// DLGN_VT fused v3:
//   out[b] = sum_{ijk} g1[b,i] g2[b,j] g3[b,k] V[i,j,k],  g_m = sigmoid(30 * x @ Wm^T)
//   B=4096, D=128, N=32.
//
// 256 blocks x 256 threads; block owns 16 batch rows.
// Stage: W(96x128) + x-tile(16x128) -> LDS (stride 132 floats, 16B-aligned, conflict-managed).
// Phase 1 (gates): thread=(b=t&15, f=6*(t>>4)+ff). Register-tiled dots from LDS:
//   per c-chunk 1 x-float4 + 6 W-float4 (4-addr multicast/wave) + 24 FMA. -> Gs[16][100].
// Phase 2 (contract): thread=(j=t>>3, kchunk=t&7). V[i][j][kchunk] in 32 float4 REGISTERS
//   (static indexing only), reused across all 16 b. Per b: g1 row in 8 float4 regs (uniform
//   broadcast), s = sum_i g1[i]*dot4(v[i],g3chunk); p = s*g2[j]; shfl_xor reduce + LDS patch.
// One dispatch, no atomics, no global scratch.

#define BETA 30.0f

__device__ __forceinline__ float f4c(const float4 v, int c) {
    // compile-time c after full unroll -> folds to a register pick
    return c == 0 ? v.x : (c == 1 ? v.y : (c == 2 ? v.z : v.w));
}

__global__ __launch_bounds__(256, 1) void dlgn_fused3_kernel(
    const float* __restrict__ x,
    const float* __restrict__ W1,
    const float* __restrict__ W2,
    const float* __restrict__ W3,
    const float* __restrict__ V,
    float* __restrict__ out)
{
    __shared__ float Wlds[96 * 132];   // 50688 B
    __shared__ float xlds[16 * 132];   //  8448 B
    __shared__ float Gs[16][100];      //  6400 B
    __shared__ float red[4][16];       //   256 B

    const int t  = threadIdx.x;
    const int b0 = blockIdx.x * 16;

    // ---- Stage W (rows 0..95) and x-tile (rows 96..111) into LDS ----
    // (96+16) rows * 32 float4 = 3584 float4 = 14 per thread, coalesced reads.
#pragma unroll
    for (int r = 0; r < 14; ++r) {
        const int idx  = r * 256 + t;   // [0,3584)
        const int row  = idx >> 5;      // 32 float4 per 128-float row
        const int col4 = idx & 31;
        float4 val;
        if (row < 96) {
            const float* Wr = (row < 32) ? (W1 + row * 128)
                            : (row < 64) ? (W2 + (row - 32) * 128)
                                         : (W3 + (row - 64) * 128);
            val = ((const float4*)Wr)[col4];
            *(float4*)&Wlds[row * 132 + col4 * 4] = val;
        } else {
            val = ((const float4*)(x + (size_t)(b0 + row - 96) * 128))[col4];
            *(float4*)&xlds[(row - 96) * 132 + col4 * 4] = val;
        }
    }
    __syncthreads();

    // ---- Phase 1: gates. thread -> (bb = t&15, f = 6*tf + ff), 16*16*6 = 1536 dots ----
    {
        const int bb = t & 15;
        const int tf = t >> 4;          // 0..15
        float acc[6] = {0.f, 0.f, 0.f, 0.f, 0.f, 0.f};
        const float4* xr = (const float4*)&xlds[bb * 132];
        const float*  w0 = &Wlds[(tf * 6) * 132];
#pragma unroll
        for (int c = 0; c < 32; ++c) {
            const float4 xv = xr[c];
#pragma unroll
            for (int ff = 0; ff < 6; ++ff) {
                const float4 wv = *(const float4*)&w0[ff * 132 + c * 4];
                acc[ff] = fmaf(xv.x, wv.x, acc[ff]);
                acc[ff] = fmaf(xv.y, wv.y, acc[ff]);
                acc[ff] = fmaf(xv.z, wv.z, acc[ff]);
                acc[ff] = fmaf(xv.w, wv.w, acc[ff]);
            }
        }
#pragma unroll
        for (int ff = 0; ff < 6; ++ff) {
            const int f = tf * 6 + ff;
            Gs[bb][f] = 1.0f / (1.0f + __expf(-BETA * acc[ff]));
        }
    }
    __syncthreads();

    // ---- Phase 2: contraction. thread -> (j = t>>3, kchunk c2 = t&7) ----
    const int j  = t >> 3;   // [0,32)
    const int c2 = t & 7;    // [0,8)

    // V[i][j][4*c2 .. 4*c2+3] for all i -> 32 float4 in registers (static idx only)
    const float4* V4 = (const float4*)V;
    float4 v[32];
#pragma unroll
    for (int i = 0; i < 32; ++i) v[i] = V4[i * 256 + t];

    const int w = t >> 6;
    const int l = t & 63;

    for (int b = 0; b < 16; ++b) {     // runtime loop: small code, regs static inside
        const float4* Gr = (const float4*)&Gs[b][0];
        float4 g1r[8];
#pragma unroll
        for (int c = 0; c < 8; ++c) g1r[c] = Gr[c];            // uniform broadcast
        const float4 g3r = *(const float4*)&Gs[b][64 + c2 * 4]; // 8 addrs, 8 banks
        const float  g2s = Gs[b][32 + j];

        float s = 0.f;
#pragma unroll
        for (int i = 0; i < 32; ++i) {
            float d4 = v[i].x * g3r.x;
            d4 = fmaf(v[i].y, g3r.y, d4);
            d4 = fmaf(v[i].z, g3r.z, d4);
            d4 = fmaf(v[i].w, g3r.w, d4);
            s = fmaf(f4c(g1r[i >> 2], i & 3), d4, s);
        }
        float p = s * g2s;
        p += __shfl_xor(p, 1);
        p += __shfl_xor(p, 2);
        p += __shfl_xor(p, 4);
        p += __shfl_xor(p, 8);
        p += __shfl_xor(p, 16);
        p += __shfl_xor(p, 32);
        if (l == 0) red[w][b] = p;
    }
    __syncthreads();

    if (t < 16) out[b0 + t] = red[0][t] + red[1][t] + red[2][t] + red[3][t];
}

extern "C" void kernel_launch(void* const* d_in, const int* in_sizes, int n_in,
                              void* d_out, int out_size, void* d_ws, size_t ws_size,
                              hipStream_t stream) {
    const float* x  = (const float*)d_in[0];
    const float* W1 = (const float*)d_in[1];
    const float* W2 = (const float*)d_in[2];
    const float* W3 = (const float*)d_in[3];
    const float* V  = (const float*)d_in[4];
    float* out = (float*)d_out;

    dlgn_fused3_kernel<<<dim3(256), dim3(256), 0, stream>>>(x, W1, W2, W3, V, out);
}